// Round 11
// baseline (266.942 us; speedup 1.0000x reference)
//
#include <hip/hip_runtime.h>
#include <hip/hip_bf16.h>
#include <math.h>

#define N_NODES 10000
#define N_EDGES 320000
#define CH 64
#define MIXW 192    // N_L * CH
#define EREC 12     // floats per edge record: sh[9] + pad -> 48B rows

// weight-image layout (shorts), stride-72 rows (16B-aligned row starts)
#define W1_OFF 0        // [64][8]
#define W2_OFF 512      // [64][72]
#define W3_OFF 5120     // [64][72]
#define W4_OFF 9728     // [192][72]
#define W_TOT 23552     // shorts
#define ACT_STRIDE 72

#define EPB 128         // edges per k_mlp block (256 thr = 4 waves, 32 edges/wave)

// fused k_pre block ranges
#define PREP_BLKS 92            // 23552/256
#define H_BLKS 2500             // 10000/4
#define HIST_BLKS 1250          // 320000/256

typedef __attribute__((ext_vector_type(8))) short bf16x8;
typedef __attribute__((ext_vector_type(4))) float f32x4;
#define MFMA16(a, b, c) __builtin_amdgcn_mfma_f32_16x16x32_bf16(a, b, c, 0, 0, 0)

// ---------- small helpers ----------
__device__ __forceinline__ float bf2f(unsigned short u) {
    union { unsigned int i; float f; } v; v.i = ((unsigned int)u) << 16; return v.f;
}
__device__ __forceinline__ unsigned short f2bf(float f) {
    unsigned int x = __float_as_uint(f);
    unsigned int r = x + 0x7fffu + ((x >> 16) & 1u);   // RNE
    return (unsigned short)(r >> 16);
}
__device__ __forceinline__ float silu(float t) {
    return t / (1.0f + __expf(-t));
}

// ---------- K_pre: fused weight-prep + linear_up + receiver histogram ----------
__global__ __launch_bounds__(256) void k_pre(const float* __restrict__ W1,
                                             const float* __restrict__ W2,
                                             const float* __restrict__ W3,
                                             const float* __restrict__ W4,
                                             unsigned short* __restrict__ wimg,
                                             const float* __restrict__ nf,
                                             const float* __restrict__ Wup,
                                             float* __restrict__ h,
                                             const int* __restrict__ recv,
                                             int* __restrict__ counts) {
    int bid = blockIdx.x;
    int t = threadIdx.x;
    if (bid < PREP_BLKS) {
        int i = bid * 256 + t;
        if (i >= W_TOT) return;
        float v;
        if (i < W2_OFF) {
            int n = i >> 3, k = i & 7;
            v = W1[k * 64 + n];
        } else if (i < W3_OFF) {
            int j = i - W2_OFF; int n = j / 72, k = j % 72;
            v = (k < 64) ? W2[k * 64 + n] : 0.f;
        } else if (i < W4_OFF) {
            int j = i - W3_OFF; int n = j / 72, k = j % 72;
            v = (k < 64) ? W3[k * 64 + n] : 0.f;
        } else {
            int j = i - W4_OFF; int n = j / 72, k = j % 72;
            v = (k < 64) ? W4[k * MIXW + n] : 0.f;
        }
        wimg[i] = f2bf(v);
    } else if (bid < PREP_BLKS + H_BLKS) {
        int node = __builtin_amdgcn_readfirstlane((bid - PREP_BLKS) * 4 + (t >> 6));
        int lane = t & 63;
        const float* nrow = nf + (size_t)node * CH;
        float acc = 0.f;
#pragma unroll
        for (int k = 0; k < CH; ++k) acc += nrow[k] * Wup[k * CH + lane];
        h[(size_t)node * CH + lane] = acc * 0.125f;
    } else {
        int e = (bid - PREP_BLKS - H_BLKS) * 256 + t;
        atomicAdd(&counts[recv[e]], 1);
    }
}

// ---------- K_scan: single-block exclusive scan over counts ----------
__global__ __launch_bounds__(1024) void k_scan(const int* __restrict__ counts,
                                               int* __restrict__ offsets,
                                               int* __restrict__ cursor) {
    __shared__ int part[1024];
    int t = threadIdx.x;
    const int CHUNK = 10;  // 1024*10 >= 10000
    int base = t * CHUNK;
    int s = 0;
    for (int i = 0; i < CHUNK; ++i) {
        int idx = base + i;
        if (idx < N_NODES) s += counts[idx];
    }
    part[t] = s;
    __syncthreads();
    for (int off = 1; off < 1024; off <<= 1) {
        int v = 0;
        if (t >= off) v = part[t - off];
        __syncthreads();
        part[t] += v;
        __syncthreads();
    }
    int run = part[t] - s;  // exclusive base for this chunk
    for (int i = 0; i < CHUNK; ++i) {
        int idx = base + i;
        if (idx < N_NODES) {
            offsets[idx] = run;
            cursor[idx] = run;
            run += counts[idx];
        }
    }
    if (t == 1023) offsets[N_NODES] = part[1023];
}

// ---------- K_mlp v6: SH + radial MLP + h-premultiply; CSR scatter inline ----------
// 256 thr = 4 waves; 128 edges/block; 32 edges/wave (two 16-row A-tiles).
// Weights from global (L2). LDS: act[128][72] bf16 + pos/snd[128] = 19.5 KB.
// h[sender] values loaded DIRECT to registers from L2 in layer 4 (coalesced
// 64B/quad segments) -- no LDS staging, no occupancy cap. Zero barriers.
__global__ __launch_bounds__(256, 4) void k_mlp(const float* __restrict__ ev,
                                                const float* __restrict__ rad,
                                                const unsigned short* __restrict__ wimg,
                                                const int* __restrict__ senders,
                                                const int* __restrict__ recv,
                                                int* __restrict__ cursor,
                                                const float* __restrict__ h,
                                                unsigned short* __restrict__ hw,
                                                float* __restrict__ erec) {
    __shared__ unsigned short act[EPB * ACT_STRIDE];     // 18432 B
    __shared__ int s_pos[EPB];                           // 512 B
    __shared__ int s_snd[EPB];                           // 512 B

    const int t = threadIdx.x;
    const int e0 = blockIdx.x * EPB;
    const int wv = t >> 6;
    const int lane = t & 63;
    const int lrow = lane & 15;
    const int quad = lane >> 4;
    const int wr0 = wv * 32;                 // this wave's first act row
    const int em0 = wr0 + lrow;              // A-tile0 row
    const int em1 = em0 + 16;                // A-tile1 row
    const int cr0 = wr0 + quad * 4;          // tile0 C-row base
    const int cr1 = cr0 + 16;                // tile1 C-row base

    // ---- phase 0 (lanes 0..31 of each wave): CSR position + sender + SH ----
    if (lane < 32) {
        int e = e0 + wr0 + lane;
        int p = atomicAdd(&cursor[recv[e]], 1);
        s_pos[wr0 + lane] = p;
        s_snd[wr0 + lane] = senders[e];
        float vx = ev[(size_t)e * 3 + 0], vy = ev[(size_t)e * 3 + 1], vz = ev[(size_t)e * 3 + 2];
        float inv = rsqrtf(vx * vx + vy * vy + vz * vz);
        float x = vx * inv, y = vy * inv, z = vz * inv;
        const float s3 = 1.7320508075688772f;
        const float s15 = 3.872983346207417f;
        const float s5 = 2.2360679774997896f;
        float4* rp = (float4*)(erec + (size_t)p * EREC);
        rp[0] = make_float4(1.0f, s3 * x, s3 * y, s3 * z);
        rp[1] = make_float4(s15 * x * y, s15 * y * z, 0.5f * s5 * (3.0f * z * z - 1.0f), s15 * x * z);
        rp[2] = make_float4(0.5f * s15 * (x * x - y * y), 0.f, 0.f, 0.f);
    }

    // ---- radial A-frags (K=8 lives in quad 0) ----
    bf16x8 ar0 = {0, 0, 0, 0, 0, 0, 0, 0};
    bf16x8 ar1 = {0, 0, 0, 0, 0, 0, 0, 0};
    if (quad == 0) {
        const float4* rp0 = (const float4*)(rad + (size_t)(e0 + em0) * 8);
        const float4* rp1 = (const float4*)(rad + (size_t)(e0 + em1) * 8);
        float4 u = rp0[0], v = rp0[1];
        ar0[0] = (short)f2bf(u.x); ar0[1] = (short)f2bf(u.y);
        ar0[2] = (short)f2bf(u.z); ar0[3] = (short)f2bf(u.w);
        ar0[4] = (short)f2bf(v.x); ar0[5] = (short)f2bf(v.y);
        ar0[6] = (short)f2bf(v.z); ar0[7] = (short)f2bf(v.w);
        u = rp1[0]; v = rp1[1];
        ar1[0] = (short)f2bf(u.x); ar1[1] = (short)f2bf(u.y);
        ar1[2] = (short)f2bf(u.z); ar1[3] = (short)f2bf(u.w);
        ar1[4] = (short)f2bf(v.x); ar1[5] = (short)f2bf(v.y);
        ar1[6] = (short)f2bf(v.z); ar1[7] = (short)f2bf(v.w);
    }

    // ---- layer 1: [8]->[64], scale 1/sqrt(8), silu ----
#pragma unroll
    for (int nt = 0; nt < 4; ++nt) {
        bf16x8 bw = {0, 0, 0, 0, 0, 0, 0, 0};
        if (quad == 0) bw = *(const bf16x8*)(wimg + W1_OFF + (nt * 16 + lrow) * 8);
        f32x4 c0 = {0.f, 0.f, 0.f, 0.f};
        f32x4 c1 = {0.f, 0.f, 0.f, 0.f};
        c0 = MFMA16(ar0, bw, c0);
        c1 = MFMA16(ar1, bw, c1);
#pragma unroll
        for (int r = 0; r < 4; ++r) {
            act[(cr0 + r) * ACT_STRIDE + nt * 16 + lrow] =
                (unsigned short)f2bf(silu(c0[r] * 0.3535533905932738f));
            act[(cr1 + r) * ACT_STRIDE + nt * 16 + lrow] =
                (unsigned short)f2bf(silu(c1[r] * 0.3535533905932738f));
        }
    }

    // ---- layers 2 & 3: [64]->[64], scale 1/8, silu, in-place per-wave ----
#pragma unroll
    for (int L = 0; L < 2; ++L) {
        const unsigned short* wbase = wimg + (L == 0 ? W2_OFF : W3_OFF);
        bf16x8 a00 = *(const bf16x8*)(act + em0 * ACT_STRIDE + quad * 8);
        bf16x8 a01 = *(const bf16x8*)(act + em0 * ACT_STRIDE + 32 + quad * 8);
        bf16x8 a10 = *(const bf16x8*)(act + em1 * ACT_STRIDE + quad * 8);
        bf16x8 a11 = *(const bf16x8*)(act + em1 * ACT_STRIDE + 32 + quad * 8);
        bf16x8 b[4][2];
#pragma unroll
        for (int nt = 0; nt < 4; ++nt)
#pragma unroll
            for (int kh = 0; kh < 2; ++kh)
                b[nt][kh] = *(const bf16x8*)(wbase + (nt * 16 + lrow) * 72 + kh * 32 + quad * 8);
#pragma unroll
        for (int nt = 0; nt < 4; ++nt) {
            f32x4 c0 = {0.f, 0.f, 0.f, 0.f};
            f32x4 c1 = {0.f, 0.f, 0.f, 0.f};
            c0 = MFMA16(a00, b[nt][0], c0);
            c0 = MFMA16(a01, b[nt][1], c0);
            c1 = MFMA16(a10, b[nt][0], c1);
            c1 = MFMA16(a11, b[nt][1], c1);
#pragma unroll
            for (int r = 0; r < 4; ++r) {
                act[(cr0 + r) * ACT_STRIDE + nt * 16 + lrow] =
                    (unsigned short)f2bf(silu(c0[r] * 0.125f));
                act[(cr1 + r) * ACT_STRIDE + nt * 16 + lrow] =
                    (unsigned short)f2bf(silu(c1[r] * 0.125f));
            }
        }
    }

    // ---- layer 4: [64]->[192], premultiplied by h[sender][col]; 3 thirds;
    //      act reused as stage; per-wave copyout to hw[pos] ----
    {
        bf16x8 a00 = *(const bf16x8*)(act + em0 * ACT_STRIDE + quad * 8);
        bf16x8 a01 = *(const bf16x8*)(act + em0 * ACT_STRIDE + 32 + quad * 8);
        bf16x8 a10 = *(const bf16x8*)(act + em1 * ACT_STRIDE + quad * 8);
        bf16x8 a11 = *(const bf16x8*)(act + em1 * ACT_STRIDE + 32 + quad * 8);

        // direct L2->register h loads: rows {cr0+r, cr1+r}, cols {ntl*16+lrow}
        // (each (row,ntl) group of 16 lanes reads a contiguous 64B segment)
        float hreg0[4][4], hreg1[4][4];
#pragma unroll
        for (int r = 0; r < 4; ++r) {
            int sn0 = s_snd[cr0 + r];
            int sn1 = s_snd[cr1 + r];
            const float* hb0 = h + (size_t)sn0 * CH + lrow;
            const float* hb1 = h + (size_t)sn1 * CH + lrow;
#pragma unroll
            for (int ntl = 0; ntl < 4; ++ntl) {
                hreg0[r][ntl] = hb0[ntl * 16];
                hreg1[r][ntl] = hb1[ntl * 16];
            }
        }

#pragma unroll
        for (int T = 0; T < 3; ++T) {
            bf16x8 b[4][2];
#pragma unroll
            for (int ntl = 0; ntl < 4; ++ntl)
#pragma unroll
                for (int kh = 0; kh < 2; ++kh)
                    b[ntl][kh] = *(const bf16x8*)(wimg + W4_OFF +
                        ((T * 4 + ntl) * 16 + lrow) * 72 + kh * 32 + quad * 8);
#pragma unroll
            for (int ntl = 0; ntl < 4; ++ntl) {
                f32x4 c0 = {0.f, 0.f, 0.f, 0.f};
                f32x4 c1 = {0.f, 0.f, 0.f, 0.f};
                c0 = MFMA16(a00, b[ntl][0], c0);
                c0 = MFMA16(a01, b[ntl][1], c0);
                c1 = MFMA16(a10, b[ntl][0], c1);
                c1 = MFMA16(a11, b[ntl][1], c1);
#pragma unroll
                for (int r = 0; r < 4; ++r) {
                    act[(cr0 + r) * ACT_STRIDE + ntl * 16 + lrow] =
                        (unsigned short)f2bf(c0[r] * 0.125f * hreg0[r][ntl]);
                    act[(cr1 + r) * ACT_STRIDE + ntl * 16 + lrow] =
                        (unsigned short)f2bf(c1[r] * 0.125f * hreg1[r][ntl]);
                }
            }
            // copy wave's 32 rows x 64 cols -> hw[pos[row]][T*64 .. T*64+64)
#pragma unroll
            for (int j = 0; j < 4; ++j) {
                int idx = lane + 64 * j;          // 0..255
                int row = idx >> 3, c8 = idx & 7;
                int p = s_pos[wr0 + row];
                uint4 v = *(const uint4*)(act + (wr0 + row) * ACT_STRIDE + c8 * 8);
                *(uint4*)(hw + (size_t)p * MIXW + T * 64 + c8 * 8) = v;
            }
        }
    }
}

// ---------- K_aggdown: pure-streaming CSR aggregation + fused linear_down ----
// One wave per node, lane = channel. ALL addresses affine in i: hw rows are
// coalesced 128B segments, erec is wave-uniform (scalarizable). No gathers.
__global__ __launch_bounds__(256, 4) void k_aggdown(const int* __restrict__ offsets,
                                                    const float* __restrict__ erec,
                                                    const unsigned short* __restrict__ hw,
                                                    const float* __restrict__ Wd,
                                                    float* __restrict__ out) {
    __shared__ float sg[4][576];
    int wv = threadIdx.x >> 6;
    int lane = threadIdx.x & 63;
    int node = __builtin_amdgcn_readfirstlane(blockIdx.x * 4 + wv);
    int s0 = __builtin_amdgcn_readfirstlane(offsets[node]);
    int s1 = __builtin_amdgcn_readfirstlane(offsets[node + 1]);
    float acc[9] = {0.f, 0.f, 0.f, 0.f, 0.f, 0.f, 0.f, 0.f, 0.f};
#pragma unroll 4
    for (int i = s0; i < s1; ++i) {
        const float* rp = erec + (size_t)i * EREC;
        const unsigned short* hrow = hw + (size_t)i * MIXW;
        float w0 = bf2f(hrow[lane]);
        float w1 = bf2f(hrow[64 + lane]);
        float w2 = bf2f(hrow[128 + lane]);
        acc[0] += w0 * rp[0];
        acc[1] += w1 * rp[1];
        acc[2] += w1 * rp[2];
        acc[3] += w1 * rp[3];
        acc[4] += w2 * rp[4];
        acc[5] += w2 * rp[5];
        acc[6] += w2 * rp[6];
        acc[7] += w2 * rp[7];
        acc[8] += w2 * rp[8];
    }
    // stash node's agg tile in LDS (per-wave region; in-order DS => no barrier)
    float* arow = sg[wv];
#pragma unroll
    for (int m = 0; m < 9; ++m) arow[lane * 9 + m] = acc[m] * (1.0f / 32.0f);

    // linear_down: lane = output channel d; arow reads broadcast
    float* orow = out + (size_t)node * 576;
    {
        float a = 0.f;
#pragma unroll
        for (int c = 0; c < 64; ++c) a += arow[c * 9] * Wd[c * 64 + lane];
        orow[lane] = a * 0.125f;
    }
    {
        float m3[3] = {0.f, 0.f, 0.f};
#pragma unroll
        for (int c = 0; c < 64; ++c) {
            float w = Wd[(64 + c) * 64 + lane];
#pragma unroll
            for (int mm = 0; mm < 3; ++mm) m3[mm] += arow[c * 9 + 1 + mm] * w;
        }
#pragma unroll
        for (int mm = 0; mm < 3; ++mm) orow[64 + lane * 3 + mm] = m3[mm] * 0.125f;
    }
    {
        float m5[5] = {0.f, 0.f, 0.f, 0.f, 0.f};
#pragma unroll
        for (int c = 0; c < 64; ++c) {
            float w = Wd[(128 + c) * 64 + lane];
#pragma unroll
            for (int mm = 0; mm < 5; ++mm) m5[mm] += arow[c * 9 + 4 + mm] * w;
        }
#pragma unroll
        for (int mm = 0; mm < 5; ++mm) orow[256 + lane * 5 + mm] = m5[mm] * 0.125f;
    }
}

// ---------- launcher ----------
static inline size_t align256(size_t x) { return (x + 255) & ~(size_t)255; }

extern "C" void kernel_launch(void* const* d_in, const int* in_sizes, int n_in,
                              void* d_out, int out_size, void* d_ws, size_t ws_size,
                              hipStream_t stream) {
    const float* edge_vectors = (const float*)d_in[0];
    const float* node_feats   = (const float*)d_in[1];
    const float* radial       = (const float*)d_in[2];
    const int*   senders      = (const int*)d_in[3];
    const int*   receivers    = (const int*)d_in[4];
    const float* W_up         = (const float*)d_in[5];
    const float* W_mlp1       = (const float*)d_in[6];
    const float* W_mlp2       = (const float*)d_in[7];
    const float* W_mlp3       = (const float*)d_in[8];
    const float* W_mlp4       = (const float*)d_in[9];
    const float* W_down       = (const float*)d_in[10];
    float* out = (float*)d_out;

    char* base = (char*)d_ws;
    size_t off = 0;
    float* h = (float*)(base + off);              off = align256(off + (size_t)N_NODES * CH * 4);
    unsigned short* hw = (unsigned short*)(base + off); off = align256(off + (size_t)N_EDGES * MIXW * 2);
    float* erec = (float*)(base + off);           off = align256(off + (size_t)N_EDGES * EREC * 4);
    unsigned short* wimg = (unsigned short*)(base + off); off = align256(off + (size_t)W_TOT * 2);
    int* counts = (int*)(base + off);             off = align256(off + (size_t)N_NODES * 4);
    int* offsets = (int*)(base + off);            off = align256(off + (size_t)(N_NODES + 1) * 4);
    int* cursor = (int*)(base + off);             off = align256(off + (size_t)N_NODES * 4);

    hipMemsetAsync(counts, 0, (size_t)N_NODES * 4, stream);

    k_pre<<<PREP_BLKS + H_BLKS + HIST_BLKS, 256, 0, stream>>>(
        W_mlp1, W_mlp2, W_mlp3, W_mlp4, wimg, node_feats, W_up, h, receivers, counts);
    k_scan<<<1, 1024, 0, stream>>>(counts, offsets, cursor);
    k_mlp<<<N_EDGES / EPB, 256, 0, stream>>>(edge_vectors, radial, wimg, senders,
                                             receivers, cursor, h, hw, erec);
    k_aggdown<<<N_NODES / 4, 256, 0, stream>>>(offsets, erec, hw, W_down, out);
}

// Round 12
// 228.456 us; speedup vs baseline: 1.1685x; 1.1685x over previous
//
#include <hip/hip_runtime.h>
#include <hip/hip_bf16.h>
#include <math.h>

#define N_NODES 10000
#define N_EDGES 320000
#define CH 64
#define MIXW 192    // N_L * CH
#define EREC 12     // floats per edge record: sh[9] + pad -> 48B rows

// weight-image layout (shorts), stride-72 rows (16B-aligned row starts)
#define W1_OFF 0        // [64][8]
#define W2_OFF 512      // [64][72]
#define W3_OFF 5120     // [64][72]
#define W4_OFF 9728     // [192][72]
#define W_TOT 23552     // shorts
#define ACT_STRIDE 72

#define EPB 128         // edges per k_mlp block (256 thr = 4 waves, 32 edges/wave)

// fused k_pre block ranges
#define PREP_BLKS 92            // 23552/256
#define H_BLKS 2500             // 10000/4
#define HIST_BLKS 1250          // 320000/256

typedef __attribute__((ext_vector_type(8))) short bf16x8;
typedef __attribute__((ext_vector_type(4))) float f32x4;
#define MFMA16(a, b, c) __builtin_amdgcn_mfma_f32_16x16x32_bf16(a, b, c, 0, 0, 0)

// ---------- small helpers ----------
__device__ __forceinline__ float bf2f(unsigned short u) {
    union { unsigned int i; float f; } v; v.i = ((unsigned int)u) << 16; return v.f;
}
__device__ __forceinline__ unsigned short f2bf(float f) {
    unsigned int x = __float_as_uint(f);
    unsigned int r = x + 0x7fffu + ((x >> 16) & 1u);   // RNE
    return (unsigned short)(r >> 16);
}
__device__ __forceinline__ float silu(float t) {
    return t / (1.0f + __expf(-t));
}

// ---------- K_pre: fused weight-prep + linear_up + receiver histogram ----------
__global__ __launch_bounds__(256) void k_pre(const float* __restrict__ W1,
                                             const float* __restrict__ W2,
                                             const float* __restrict__ W3,
                                             const float* __restrict__ W4,
                                             unsigned short* __restrict__ wimg,
                                             const float* __restrict__ nf,
                                             const float* __restrict__ Wup,
                                             float* __restrict__ h,
                                             const int* __restrict__ recv,
                                             int* __restrict__ counts) {
    int bid = blockIdx.x;
    int t = threadIdx.x;
    if (bid < PREP_BLKS) {
        int i = bid * 256 + t;
        if (i >= W_TOT) return;
        float v;
        if (i < W2_OFF) {
            int n = i >> 3, k = i & 7;
            v = W1[k * 64 + n];
        } else if (i < W3_OFF) {
            int j = i - W2_OFF; int n = j / 72, k = j % 72;
            v = (k < 64) ? W2[k * 64 + n] : 0.f;
        } else if (i < W4_OFF) {
            int j = i - W3_OFF; int n = j / 72, k = j % 72;
            v = (k < 64) ? W3[k * 64 + n] : 0.f;
        } else {
            int j = i - W4_OFF; int n = j / 72, k = j % 72;
            v = (k < 64) ? W4[k * MIXW + n] : 0.f;
        }
        wimg[i] = f2bf(v);
    } else if (bid < PREP_BLKS + H_BLKS) {
        int node = __builtin_amdgcn_readfirstlane((bid - PREP_BLKS) * 4 + (t >> 6));
        int lane = t & 63;
        const float* nrow = nf + (size_t)node * CH;
        float acc = 0.f;
#pragma unroll
        for (int k = 0; k < CH; ++k) acc += nrow[k] * Wup[k * CH + lane];
        h[(size_t)node * CH + lane] = acc * 0.125f;
    } else {
        int e = (bid - PREP_BLKS - H_BLKS) * 256 + t;
        atomicAdd(&counts[recv[e]], 1);
    }
}

// ---------- K_scan: single-block exclusive scan over counts ----------
__global__ __launch_bounds__(1024) void k_scan(const int* __restrict__ counts,
                                               int* __restrict__ offsets,
                                               int* __restrict__ cursor) {
    __shared__ int part[1024];
    int t = threadIdx.x;
    const int CHUNK = 10;  // 1024*10 >= 10000
    int base = t * CHUNK;
    int s = 0;
    for (int i = 0; i < CHUNK; ++i) {
        int idx = base + i;
        if (idx < N_NODES) s += counts[idx];
    }
    part[t] = s;
    __syncthreads();
    for (int off = 1; off < 1024; off <<= 1) {
        int v = 0;
        if (t >= off) v = part[t - off];
        __syncthreads();
        part[t] += v;
        __syncthreads();
    }
    int run = part[t] - s;  // exclusive base for this chunk
    for (int i = 0; i < CHUNK; ++i) {
        int idx = base + i;
        if (idx < N_NODES) {
            offsets[idx] = run;
            cursor[idx] = run;
            run += counts[idx];
        }
    }
    if (t == 1023) offsets[N_NODES] = part[1023];
}

// ---------- K_mlp v7: SH + radial MLP + h-premultiply; CSR scatter inline ----------
// 256 thr = 4 waves; 128 edges/block; 32 edges/wave (two 16-row A-tiles).
// Weights from global (L2). LDS: act[128][72] bf16 + pos/snd[128] = 19.5 KB.
// h[sender] loaded direct L2->register in layer 4 (coalesced 64B/quad).
// NOTE: no min-waves launch bound here -- R11's (256,4) made the allocator
// spill the 32-float hreg arrays to scratch (+82 MB WRITE). Let VGPRs float.
__global__ __launch_bounds__(256) void k_mlp(const float* __restrict__ ev,
                                             const float* __restrict__ rad,
                                             const unsigned short* __restrict__ wimg,
                                             const int* __restrict__ senders,
                                             const int* __restrict__ recv,
                                             int* __restrict__ cursor,
                                             const float* __restrict__ h,
                                             unsigned short* __restrict__ hw,
                                             float* __restrict__ erec) {
    __shared__ unsigned short act[EPB * ACT_STRIDE];     // 18432 B
    __shared__ int s_pos[EPB];                           // 512 B
    __shared__ int s_snd[EPB];                           // 512 B

    const int t = threadIdx.x;
    const int e0 = blockIdx.x * EPB;
    const int wv = t >> 6;
    const int lane = t & 63;
    const int lrow = lane & 15;
    const int quad = lane >> 4;
    const int wr0 = wv * 32;                 // this wave's first act row
    const int em0 = wr0 + lrow;              // A-tile0 row
    const int em1 = em0 + 16;                // A-tile1 row
    const int cr0 = wr0 + quad * 4;          // tile0 C-row base
    const int cr1 = cr0 + 16;                // tile1 C-row base

    // ---- phase 0 (lanes 0..31 of each wave): CSR position + sender + SH ----
    if (lane < 32) {
        int e = e0 + wr0 + lane;
        int p = atomicAdd(&cursor[recv[e]], 1);
        s_pos[wr0 + lane] = p;
        s_snd[wr0 + lane] = senders[e];
        float vx = ev[(size_t)e * 3 + 0], vy = ev[(size_t)e * 3 + 1], vz = ev[(size_t)e * 3 + 2];
        float inv = rsqrtf(vx * vx + vy * vy + vz * vz);
        float x = vx * inv, y = vy * inv, z = vz * inv;
        const float s3 = 1.7320508075688772f;
        const float s15 = 3.872983346207417f;
        const float s5 = 2.2360679774997896f;
        float4* rp = (float4*)(erec + (size_t)p * EREC);
        rp[0] = make_float4(1.0f, s3 * x, s3 * y, s3 * z);
        rp[1] = make_float4(s15 * x * y, s15 * y * z, 0.5f * s5 * (3.0f * z * z - 1.0f), s15 * x * z);
        rp[2] = make_float4(0.5f * s15 * (x * x - y * y), 0.f, 0.f, 0.f);
    }

    // ---- radial A-frags (K=8 lives in quad 0) ----
    bf16x8 ar0 = {0, 0, 0, 0, 0, 0, 0, 0};
    bf16x8 ar1 = {0, 0, 0, 0, 0, 0, 0, 0};
    if (quad == 0) {
        const float4* rp0 = (const float4*)(rad + (size_t)(e0 + em0) * 8);
        const float4* rp1 = (const float4*)(rad + (size_t)(e0 + em1) * 8);
        float4 u = rp0[0], v = rp0[1];
        ar0[0] = (short)f2bf(u.x); ar0[1] = (short)f2bf(u.y);
        ar0[2] = (short)f2bf(u.z); ar0[3] = (short)f2bf(u.w);
        ar0[4] = (short)f2bf(v.x); ar0[5] = (short)f2bf(v.y);
        ar0[6] = (short)f2bf(v.z); ar0[7] = (short)f2bf(v.w);
        u = rp1[0]; v = rp1[1];
        ar1[0] = (short)f2bf(u.x); ar1[1] = (short)f2bf(u.y);
        ar1[2] = (short)f2bf(u.z); ar1[3] = (short)f2bf(u.w);
        ar1[4] = (short)f2bf(v.x); ar1[5] = (short)f2bf(v.y);
        ar1[6] = (short)f2bf(v.z); ar1[7] = (short)f2bf(v.w);
    }

    // ---- layer 1: [8]->[64], scale 1/sqrt(8), silu ----
#pragma unroll
    for (int nt = 0; nt < 4; ++nt) {
        bf16x8 bw = {0, 0, 0, 0, 0, 0, 0, 0};
        if (quad == 0) bw = *(const bf16x8*)(wimg + W1_OFF + (nt * 16 + lrow) * 8);
        f32x4 c0 = {0.f, 0.f, 0.f, 0.f};
        f32x4 c1 = {0.f, 0.f, 0.f, 0.f};
        c0 = MFMA16(ar0, bw, c0);
        c1 = MFMA16(ar1, bw, c1);
#pragma unroll
        for (int r = 0; r < 4; ++r) {
            act[(cr0 + r) * ACT_STRIDE + nt * 16 + lrow] =
                (unsigned short)f2bf(silu(c0[r] * 0.3535533905932738f));
            act[(cr1 + r) * ACT_STRIDE + nt * 16 + lrow] =
                (unsigned short)f2bf(silu(c1[r] * 0.3535533905932738f));
        }
    }

    // ---- layers 2 & 3: [64]->[64], scale 1/8, silu, in-place per-wave ----
#pragma unroll
    for (int L = 0; L < 2; ++L) {
        const unsigned short* wbase = wimg + (L == 0 ? W2_OFF : W3_OFF);
        bf16x8 a00 = *(const bf16x8*)(act + em0 * ACT_STRIDE + quad * 8);
        bf16x8 a01 = *(const bf16x8*)(act + em0 * ACT_STRIDE + 32 + quad * 8);
        bf16x8 a10 = *(const bf16x8*)(act + em1 * ACT_STRIDE + quad * 8);
        bf16x8 a11 = *(const bf16x8*)(act + em1 * ACT_STRIDE + 32 + quad * 8);
        bf16x8 b[4][2];
#pragma unroll
        for (int nt = 0; nt < 4; ++nt)
#pragma unroll
            for (int kh = 0; kh < 2; ++kh)
                b[nt][kh] = *(const bf16x8*)(wbase + (nt * 16 + lrow) * 72 + kh * 32 + quad * 8);
#pragma unroll
        for (int nt = 0; nt < 4; ++nt) {
            f32x4 c0 = {0.f, 0.f, 0.f, 0.f};
            f32x4 c1 = {0.f, 0.f, 0.f, 0.f};
            c0 = MFMA16(a00, b[nt][0], c0);
            c0 = MFMA16(a01, b[nt][1], c0);
            c1 = MFMA16(a10, b[nt][0], c1);
            c1 = MFMA16(a11, b[nt][1], c1);
#pragma unroll
            for (int r = 0; r < 4; ++r) {
                act[(cr0 + r) * ACT_STRIDE + nt * 16 + lrow] =
                    (unsigned short)f2bf(silu(c0[r] * 0.125f));
                act[(cr1 + r) * ACT_STRIDE + nt * 16 + lrow] =
                    (unsigned short)f2bf(silu(c1[r] * 0.125f));
            }
        }
    }

    // ---- layer 4: [64]->[192], premultiplied by h[sender][col]; 3 thirds;
    //      act reused as stage; per-wave copyout to hw[pos] ----
    {
        bf16x8 a00 = *(const bf16x8*)(act + em0 * ACT_STRIDE + quad * 8);
        bf16x8 a01 = *(const bf16x8*)(act + em0 * ACT_STRIDE + 32 + quad * 8);
        bf16x8 a10 = *(const bf16x8*)(act + em1 * ACT_STRIDE + quad * 8);
        bf16x8 a11 = *(const bf16x8*)(act + em1 * ACT_STRIDE + 32 + quad * 8);

        // direct L2->register h loads: rows {cr0+r, cr1+r}, cols {ntl*16+lrow}
        // (each (row,ntl) group of 16 lanes reads a contiguous 64B segment)
        float hreg0[4][4], hreg1[4][4];
#pragma unroll
        for (int r = 0; r < 4; ++r) {
            int sn0 = s_snd[cr0 + r];
            int sn1 = s_snd[cr1 + r];
            const float* hb0 = h + (size_t)sn0 * CH + lrow;
            const float* hb1 = h + (size_t)sn1 * CH + lrow;
#pragma unroll
            for (int ntl = 0; ntl < 4; ++ntl) {
                hreg0[r][ntl] = hb0[ntl * 16];
                hreg1[r][ntl] = hb1[ntl * 16];
            }
        }

#pragma unroll
        for (int T = 0; T < 3; ++T) {
            bf16x8 b[4][2];
#pragma unroll
            for (int ntl = 0; ntl < 4; ++ntl)
#pragma unroll
                for (int kh = 0; kh < 2; ++kh)
                    b[ntl][kh] = *(const bf16x8*)(wimg + W4_OFF +
                        ((T * 4 + ntl) * 16 + lrow) * 72 + kh * 32 + quad * 8);
#pragma unroll
            for (int ntl = 0; ntl < 4; ++ntl) {
                f32x4 c0 = {0.f, 0.f, 0.f, 0.f};
                f32x4 c1 = {0.f, 0.f, 0.f, 0.f};
                c0 = MFMA16(a00, b[ntl][0], c0);
                c0 = MFMA16(a01, b[ntl][1], c0);
                c1 = MFMA16(a10, b[ntl][0], c1);
                c1 = MFMA16(a11, b[ntl][1], c1);
#pragma unroll
                for (int r = 0; r < 4; ++r) {
                    act[(cr0 + r) * ACT_STRIDE + ntl * 16 + lrow] =
                        (unsigned short)f2bf(c0[r] * 0.125f * hreg0[r][ntl]);
                    act[(cr1 + r) * ACT_STRIDE + ntl * 16 + lrow] =
                        (unsigned short)f2bf(c1[r] * 0.125f * hreg1[r][ntl]);
                }
            }
            // copy wave's 32 rows x 64 cols -> hw[pos[row]][T*64 .. T*64+64)
#pragma unroll
            for (int j = 0; j < 4; ++j) {
                int idx = lane + 64 * j;          // 0..255
                int row = idx >> 3, c8 = idx & 7;
                int p = s_pos[wr0 + row];
                uint4 v = *(const uint4*)(act + (wr0 + row) * ACT_STRIDE + c8 * 8);
                *(uint4*)(hw + (size_t)p * MIXW + T * 64 + c8 * 8) = v;
            }
        }
    }
}

// ---------- K_aggdown: pure-streaming CSR aggregation + fused linear_down ----
// One wave per node, lane = channel. ALL addresses affine in i: hw rows are
// coalesced 128B segments, erec is wave-uniform (scalarizable). No gathers.
__global__ __launch_bounds__(256, 4) void k_aggdown(const int* __restrict__ offsets,
                                                    const float* __restrict__ erec,
                                                    const unsigned short* __restrict__ hw,
                                                    const float* __restrict__ Wd,
                                                    float* __restrict__ out) {
    __shared__ float sg[4][576];
    int wv = threadIdx.x >> 6;
    int lane = threadIdx.x & 63;
    int node = __builtin_amdgcn_readfirstlane(blockIdx.x * 4 + wv);
    int s0 = __builtin_amdgcn_readfirstlane(offsets[node]);
    int s1 = __builtin_amdgcn_readfirstlane(offsets[node + 1]);
    float acc[9] = {0.f, 0.f, 0.f, 0.f, 0.f, 0.f, 0.f, 0.f, 0.f};
#pragma unroll 4
    for (int i = s0; i < s1; ++i) {
        const float* rp = erec + (size_t)i * EREC;
        const unsigned short* hrow = hw + (size_t)i * MIXW;
        float w0 = bf2f(hrow[lane]);
        float w1 = bf2f(hrow[64 + lane]);
        float w2 = bf2f(hrow[128 + lane]);
        acc[0] += w0 * rp[0];
        acc[1] += w1 * rp[1];
        acc[2] += w1 * rp[2];
        acc[3] += w1 * rp[3];
        acc[4] += w2 * rp[4];
        acc[5] += w2 * rp[5];
        acc[6] += w2 * rp[6];
        acc[7] += w2 * rp[7];
        acc[8] += w2 * rp[8];
    }
    // stash node's agg tile in LDS (per-wave region; in-order DS => no barrier)
    float* arow = sg[wv];
#pragma unroll
    for (int m = 0; m < 9; ++m) arow[lane * 9 + m] = acc[m] * (1.0f / 32.0f);

    // linear_down: lane = output channel d; arow reads broadcast
    float* orow = out + (size_t)node * 576;
    {
        float a = 0.f;
#pragma unroll
        for (int c = 0; c < 64; ++c) a += arow[c * 9] * Wd[c * 64 + lane];
        orow[lane] = a * 0.125f;
    }
    {
        float m3[3] = {0.f, 0.f, 0.f};
#pragma unroll
        for (int c = 0; c < 64; ++c) {
            float w = Wd[(64 + c) * 64 + lane];
#pragma unroll
            for (int mm = 0; mm < 3; ++mm) m3[mm] += arow[c * 9 + 1 + mm] * w;
        }
#pragma unroll
        for (int mm = 0; mm < 3; ++mm) orow[64 + lane * 3 + mm] = m3[mm] * 0.125f;
    }
    {
        float m5[5] = {0.f, 0.f, 0.f, 0.f, 0.f};
#pragma unroll
        for (int c = 0; c < 64; ++c) {
            float w = Wd[(128 + c) * 64 + lane];
#pragma unroll
            for (int mm = 0; mm < 5; ++mm) m5[mm] += arow[c * 9 + 4 + mm] * w;
        }
#pragma unroll
        for (int mm = 0; mm < 5; ++mm) orow[256 + lane * 5 + mm] = m5[mm] * 0.125f;
    }
}

// ---------- launcher ----------
static inline size_t align256(size_t x) { return (x + 255) & ~(size_t)255; }

extern "C" void kernel_launch(void* const* d_in, const int* in_sizes, int n_in,
                              void* d_out, int out_size, void* d_ws, size_t ws_size,
                              hipStream_t stream) {
    const float* edge_vectors = (const float*)d_in[0];
    const float* node_feats   = (const float*)d_in[1];
    const float* radial       = (const float*)d_in[2];
    const int*   senders      = (const int*)d_in[3];
    const int*   receivers    = (const int*)d_in[4];
    const float* W_up         = (const float*)d_in[5];
    const float* W_mlp1       = (const float*)d_in[6];
    const float* W_mlp2       = (const float*)d_in[7];
    const float* W_mlp3       = (const float*)d_in[8];
    const float* W_mlp4       = (const float*)d_in[9];
    const float* W_down       = (const float*)d_in[10];
    float* out = (float*)d_out;

    char* base = (char*)d_ws;
    size_t off = 0;
    float* h = (float*)(base + off);              off = align256(off + (size_t)N_NODES * CH * 4);
    unsigned short* hw = (unsigned short*)(base + off); off = align256(off + (size_t)N_EDGES * MIXW * 2);
    float* erec = (float*)(base + off);           off = align256(off + (size_t)N_EDGES * EREC * 4);
    unsigned short* wimg = (unsigned short*)(base + off); off = align256(off + (size_t)W_TOT * 2);
    int* counts = (int*)(base + off);             off = align256(off + (size_t)N_NODES * 4);
    int* offsets = (int*)(base + off);            off = align256(off + (size_t)(N_NODES + 1) * 4);
    int* cursor = (int*)(base + off);             off = align256(off + (size_t)N_NODES * 4);

    hipMemsetAsync(counts, 0, (size_t)N_NODES * 4, stream);

    k_pre<<<PREP_BLKS + H_BLKS + HIST_BLKS, 256, 0, stream>>>(
        W_mlp1, W_mlp2, W_mlp3, W_mlp4, wimg, node_feats, W_up, h, receivers, counts);
    k_scan<<<1, 1024, 0, stream>>>(counts, offsets, cursor);
    k_mlp<<<N_EDGES / EPB, 256, 0, stream>>>(edge_vectors, radial, wimg, senders,
                                             receivers, cursor, h, hw, erec);
    k_aggdown<<<N_NODES / 4, 256, 0, stream>>>(offsets, erec, hw, W_down, out);
}